// Round 1
// baseline (855.165 us; speedup 1.0000x reference)
//
#include <hip/hip_runtime.h>
#include <stdint.h>

#define BB 1024
#define SS 1024
#define TT 20

#define L2 16
#define C2 (SS / L2)  // 64 chunks for backtrack

// ---------------------------------------------------------------------------
// Forward Viterbi: one wave (64 threads) per batch. Lane j owns tag j (j<20).
// Score vector lives distributed across lanes; broadcast via __shfl (readlane).
// trans column j hoisted into registers. Backpointers (uint8) -> d_ws.
// ---------------------------------------------------------------------------
__global__ __launch_bounds__(64) void fwd_kernel(
    const float* __restrict__ em,      // [B,S,T]
    const float* __restrict__ startt,  // [T]
    const float* __restrict__ endt,    // [T]
    const float* __restrict__ trans,   // [T,T]
    uint8_t* __restrict__ bp,          // [S,B,T] (s>=1 used)
    int* __restrict__ last_tag)        // [B]
{
    const int b = blockIdx.x;
    const int lane = threadIdx.x;
    const int j = (lane < TT) ? lane : (TT - 1);  // lanes >=20 shadow j=19

    // trans column j into registers (20 VGPRs)
    float tr[TT];
#pragma unroll
    for (int i = 0; i < TT; ++i) tr[i] = trans[i * TT + j];

    const float* emb = em + (size_t)b * SS * TT;
    float score = startt[j] + emb[j];  // s = 0

    // distance-2 emission prefetch
    float e1 = emb[1 * TT + j];
    float e2 = emb[2 * TT + j];

    uint8_t* bpb = bp + (size_t)b * TT;

    for (int s = 1; s < SS; ++s) {
        const int sn = (s + 2 < SS) ? (s + 2) : (SS - 1);
        float enext = emb[(size_t)sn * TT + j];
        float ecur = e1; e1 = e2; e2 = enext;

        // best over i of score[i] + trans[i][j], first-index argmax
        float best;
        int bpi = 0;
        {
            float v0 = __shfl(score, 0, 64);
            best = v0 + tr[0];
        }
#pragma unroll
        for (int i = 1; i < TT; ++i) {
            float v = __shfl(score, i, 64);
            float cand = v + tr[i];
            bool gt = cand > best;   // strict > keeps first max (jnp.argmax)
            best = gt ? cand : best;
            bpi = gt ? i : bpi;
        }
        score = best + ecur;
        if (lane < TT) bpb[(size_t)s * BB * TT + lane] = (uint8_t)bpi;
    }

    // final argmax over tags (uniform across lanes via shfl)
    float fin = score + endt[j];
    float bestf = __shfl(fin, 0, 64);
    int bt = 0;
#pragma unroll
    for (int i = 1; i < TT; ++i) {
        float v = __shfl(fin, i, 64);
        bool gt = v > bestf;
        bestf = gt ? v : bestf;
        bt = gt ? i : bt;
    }
    if (lane == 0) last_tag[b] = bt;
}

// ---------------------------------------------------------------------------
// Backtrack phase 1: compose per-chunk pointer maps.
// G_c[j] = tag[c*L2 - 1] given tag[(c+1)*L2 - 1] = j   (c = 1..C2-1)
// ---------------------------------------------------------------------------
__global__ void bt_compose(const uint8_t* __restrict__ bp, uint8_t* __restrict__ G)
{
    const int tid = blockIdx.x * blockDim.x + threadIdx.x;
    const int total = BB * (C2 - 1) * TT;
    if (tid >= total) return;
    const int j = tid % TT;
    const int r = tid / TT;
    const int c = 1 + (r % (C2 - 1));
    const int b = r / (C2 - 1);

    int t = j;
    const int hi = (c + 1) * L2 - 1;
#pragma unroll
    for (int k = 0; k < L2; ++k) {
        const int s = hi - k;
        t = bp[((size_t)s * BB + b) * TT + t];
    }
    G[((size_t)c * BB + b) * TT + j] = (uint8_t)t;
}

// ---------------------------------------------------------------------------
// Backtrack phase 2: serial scan over chunk boundaries (per batch).
// xtag[c][b] = tag[(c+1)*L2 - 1]
// ---------------------------------------------------------------------------
__global__ void bt_scan(const uint8_t* __restrict__ G,
                        const int* __restrict__ last_tag,
                        int* __restrict__ xtag)
{
    const int b = blockIdx.x * blockDim.x + threadIdx.x;
    if (b >= BB) return;
    int x = last_tag[b];
    xtag[(size_t)(C2 - 1) * BB + b] = x;
    for (int c = C2 - 1; c >= 1; --c) {
        x = G[((size_t)c * BB + b) * TT + x];
        xtag[(size_t)(c - 1) * BB + b] = x;
    }
}

// ---------------------------------------------------------------------------
// Backtrack phase 3: expand within each chunk, write int32 tags.
// ---------------------------------------------------------------------------
__global__ void bt_expand(const uint8_t* __restrict__ bp,
                          const int* __restrict__ xtag,
                          int* __restrict__ out)
{
    const int tid = blockIdx.x * blockDim.x + threadIdx.x;
    if (tid >= BB * C2) return;
    const int c = tid % C2;
    const int b = tid / C2;

    int t = xtag[(size_t)c * BB + b];
    const int hi = (c + 1) * L2 - 1;
    int* ob = out + (size_t)b * SS;
    ob[hi] = t;
#pragma unroll
    for (int k = 0; k < L2 - 1; ++k) {
        const int s = hi - k;
        t = bp[((size_t)s * BB + b) * TT + t];
        ob[s - 1] = t;
    }
}

extern "C" void kernel_launch(void* const* d_in, const int* in_sizes, int n_in,
                              void* d_out, int out_size, void* d_ws, size_t ws_size,
                              hipStream_t stream) {
    const float* em = (const float*)d_in[0];   // emissions [B,S,T]
    const float* st = (const float*)d_in[1];   // start_transitions [T]
    const float* en = (const float*)d_in[2];   // end_transitions [T]
    const float* tr = (const float*)d_in[3];   // transitions [T,T]
    int* out = (int*)d_out;                    // [B,S] int32

    // workspace layout
    const size_t SBT = (size_t)SS * BB * TT;            // 20.97 MB backpointers
    uint8_t* bp = (uint8_t*)d_ws;
    int* last_tag = (int*)((char*)d_ws + SBT);          // 4 KB
    uint8_t* G = (uint8_t*)d_ws + SBT + 4096;           // C2*B*T = 1.31 MB
    int* xtag = (int*)((char*)d_ws + SBT + 4096 + (size_t)C2 * BB * TT);  // 256 KB

    fwd_kernel<<<BB, 64, 0, stream>>>(em, st, en, tr, bp, last_tag);

    const int tot1 = BB * (C2 - 1) * TT;
    bt_compose<<<(tot1 + 255) / 256, 256, 0, stream>>>(bp, G);
    bt_scan<<<(BB + 255) / 256, 256, 0, stream>>>(G, last_tag, xtag);
    bt_expand<<<(BB * C2 + 255) / 256, 256, 0, stream>>>(bp, xtag, out);
}